// Round 23
// baseline (39.682 us; speedup 1.0000x reference)
//
#include <hip/hip_runtime.h>
#include <math.h>

#define LMAXC 12
#define DIM   512
#define VOC   1552
#define NCHAR 80
#define SCALE     4096.0f
#define INV_SCALE (1.0f/4096.0f)
#define NLOG2E    (-1.4426950408889634f)

typedef float vf4 __attribute__((ext_vector_type(4)));
typedef float vf2 __attribute__((ext_vector_type(2)));
typedef unsigned short ushort_t;

// ws layout (float units):
//   [0, 4096)     ww8 accumulator slices (8 x 512 fp32)
//   byte 16384    u8 table: 81 rows x 512 fp8 bytes, COLUMN-PERMUTED,
//                 values pre-scaled by SCALE*NLOG2E (fits e4m3 range)
#define WW8_OFF 0
#define U_BYTE_OFF 16384

__device__ __forceinline__ float rcp_fast(float x) {
#if __has_builtin(__builtin_amdgcn_rcpf)
    return __builtin_amdgcn_rcpf(x);
#else
    return 1.0f / x;
#endif
}
__device__ __forceinline__ float exp2_fast(float x) {
#if __has_builtin(__builtin_amdgcn_exp2f)
    return __builtin_amdgcn_exp2f(x);
#else
    return __expf(x * 0.69314718056f);
#endif
}

// Wave-wide sum via DPP (VALU-only) -> uniform value (readlane 63).
__device__ __forceinline__ float wave_sum_bcast(float x) {
    float s = x;
    s += __int_as_float(__builtin_amdgcn_update_dpp(0, __float_as_int(s), 0x111, 0xf, 0xf, true)); // row_shr:1
    s += __int_as_float(__builtin_amdgcn_update_dpp(0, __float_as_int(s), 0x112, 0xf, 0xf, true)); // row_shr:2
    s += __int_as_float(__builtin_amdgcn_update_dpp(0, __float_as_int(s), 0x114, 0xf, 0xf, true)); // row_shr:4
    s += __int_as_float(__builtin_amdgcn_update_dpp(0, __float_as_int(s), 0x118, 0xf, 0xf, true)); // row_shr:8
    s += __int_as_float(__builtin_amdgcn_update_dpp(0, __float_as_int(s), 0x142, 0xf, 0xf, true)); // row_bcast:15
    s += __int_as_float(__builtin_amdgcn_update_dpp(0, __float_as_int(s), 0x143, 0xf, 0xf, true)); // row_bcast:31
    return __int_as_float(__builtin_amdgcn_readlane(__float_as_int(s), 63));
}

#if __has_builtin(__builtin_amdgcn_cvt_pk_fp8_f32) && __has_builtin(__builtin_amdgcn_cvt_pk_f32_fp8)
#define HW_FP8 1
#else
#define HW_FP8 0
#endif

#if !HW_FP8
__device__ __forceinline__ unsigned char f2fp8_sw(float f) {
    unsigned u = __float_as_uint(f);
    unsigned s = (u >> 24) & 0x80u;
    float a = fabsf(f);
    if (a < 0.015625f) return (unsigned char)s;
    if (a > 448.f) a = 448.f;
    u = __float_as_uint(a);
    u = u + 0x7ffffu + ((u >> 20) & 1u);
    int e8 = (int)(u >> 23) - 120;
    if (e8 <= 0) return (unsigned char)s;
    if (e8 > 15) e8 = 15;
    return (unsigned char)(s | (e8 << 3) | ((u >> 20) & 7u));
}
__device__ __forceinline__ float fp8_to_f32_sw(unsigned b) {
    unsigned e = (b >> 3) & 15u, m = b & 7u, s = (b & 0x80u) << 24;
    if (e == 0) return __uint_as_float(s);
    return __uint_as_float(s | ((e + 120u) << 23) | (m << 20));
}
#endif

// HI must be a compile-time constant for the builtin.
template<bool HI>
__device__ __forceinline__ vf2 cvt2_fp8(unsigned w32) {
#if HW_FP8
    return __builtin_amdgcn_cvt_pk_f32_fp8((int)w32, HI);
#else
    vf2 r;
    if (HI) { r.x = fp8_to_f32_sw((w32 >> 16) & 0xffu); r.y = fp8_to_f32_sw(w32 >> 24); }
    else    { r.x = fp8_to_f32_sw(w32 & 0xffu);         r.y = fp8_to_f32_sw((w32 >> 8) & 0xffu); }
    return r;
#endif
}

__device__ __forceinline__ ushort_t pack2_fp8(float f0, float f1) {
#if HW_FP8
    return (ushort_t)(__builtin_amdgcn_cvt_pk_fp8_f32(f0, f1, 0, false) & 0xffffu);
#else
    return (ushort_t)(f2fp8_sw(f0) | ((unsigned)f2fp8_sw(f1) << 8));
#endif
}

// grid = NCHAR + 1 = 81 blocks (wtab conversion removed)
__global__ __launch_bounds__(256)
void setup_kernel(const float* __restrict__ ctab,
                  const float* __restrict__ cpw,
                  const float* __restrict__ cpb,
                  float*       __restrict__ ws)
{
    __shared__ float red[4];
    const int b   = blockIdx.x;
    const int tid = threadIdx.x;
    unsigned char* u8 = (unsigned char*)ws + U_BYTE_OFF;

    if (b < NCHAR) {
        const float a0 = ctab[b * DIM + 2 * tid];
        const float a1 = ctab[b * DIM + 2 * tid + 1];
        float p = a0 * cpw[2 * tid] + a1 * cpw[2 * tid + 1];
        #pragma unroll
        for (int off = 32; off > 0; off >>= 1) p += __shfl_xor(p, off, 64);
        if ((tid & 63) == 0) red[tid >> 6] = p;
        __syncthreads();
        // fold SCALE (fp8 range) AND NLOG2E (gate exp2) into the table
        const float s = (red[0] + red[1] + red[2] + red[3] + cpb[0]) * SCALE * NLOG2E;
        const int q   = (tid < 128) ? (tid >> 1) : ((tid - 128) >> 1);
        const int pos = 8 * q + ((tid & 1) << 1) + ((tid < 128) ? 0 : 4);
        ((ushort_t*)(u8 + b * DIM))[pos >> 1] = pack2_fp8(s * a0, s * a1);
    } else {
        for (int i = tid; i < 8 * DIM; i += 256) ws[WW8_OFF + i] = 0.f;
        if (tid < 128) ((unsigned int*)(u8 + NCHAR * DIM))[tid] = 0u;  // zeros row
    }
}

// R22 structure; wtab read DIRECTLY as f32 (two contiguous vf4 loads/lane),
// INV_SCALE applied to we at consume; u-table carries SCALE*NLOG2E.
__global__ __launch_bounds__(512)
void fused_word_kernel(const int*   __restrict__ word_ids,
                       const int*   __restrict__ char_ids,
                       const int*   __restrict__ char_lens,
                       const float* __restrict__ wtab,
                       const float* __restrict__ wpw,
                       const float* __restrict__ wpb,
                       const float* __restrict__ ws,
                       float*       __restrict__ all_embed, // [N, 512]
                       float*       __restrict__ ww8,       // [8, 512]
                       int n)
{
    __shared__ __align__(16) unsigned char smem[41472];   // 81 rows x 512 fp8 (permuted)

    {
        const uint4* src = (const uint4*)((const unsigned char*)ws + U_BYTE_OFF);
        uint4* dst = (uint4*)smem;
        for (int i = threadIdx.x; i < 2592; i += 512) dst[i] = src[i];
    }
    __syncthreads();

    const int lane = threadIdx.x & 63;
    const int wv   = threadIdx.x >> 6;               // 0..7
    const int dA   = lane << 2;                      // dims [4l, 4l+4)
    const int dB   = 256 + (lane << 2);

    // word_proj weights as pairs
    const vf2 pw0 = *(const vf2*)(wpw + dA);
    const vf2 pw1 = *(const vf2*)(wpw + dA + 2);
    const vf2 pw2 = *(const vf2*)(wpw + dB);
    const vf2 pw3 = *(const vf2*)(wpw + dB + 2);
    const float wb = wpb[0];

    vf2 acc0 = {0.f, 0.f}, acc1 = acc0, acc2 = acc0, acc3 = acc0;

    const int gw0     = (blockIdx.x << 3) + wv;
    const int gstride = gridDim.x << 3;

    int wu = 0, len = 0;
    int4 ci0 = {0,0,0,0}, ci1 = ci0, ci2 = ci0;
    vf4 weA = {0.f,0.f,0.f,0.f}, weB = weA;

    // deferred-store state
    int wp = -1;
    vf4 sAv = {0.f,0.f,0.f,0.f}, sBv = sAv;

    int w = gw0;
    if (w < n) {
        wu  = __builtin_amdgcn_readfirstlane(w);
        const int wid = word_ids[wu];
        len = char_lens[wu];
        const int4* cp = (const int4*)(char_ids + (size_t)wu * LMAXC);
        ci0 = cp[0]; ci1 = cp[1]; ci2 = cp[2];
        const float* wr = wtab + (size_t)wid * DIM;
        weA = *(const vf4*)(wr + dA);
        weB = *(const vf4*)(wr + dB);
    }

    while (w < n) {
        const int wn   = w + gstride;
        const int wun  = __builtin_amdgcn_readfirstlane(wn < n ? wn : 0);
        const int widn = word_ids[wun];
        const int lenn = char_lens[wun];
        const int4* cpn = (const int4*)(char_ids + (size_t)wun * LMAXC);
        const int4 m0 = cpn[0], m1 = cpn[1], m2 = cpn[2];
        const float* wrn = wtab + (size_t)widn * DIM;
        const vf4 weAn = *(const vf4*)(wrn + dA);
        const vf4 weBn = *(const vf4*)(wrn + dB);

        const int cid[LMAXC] = {ci0.x, ci0.y, ci0.z, ci0.w,
                                ci1.x, ci1.y, ci1.z, ci1.w,
                                ci2.x, ci2.y, ci2.z, ci2.w};
        int cide[LMAXC];
        #pragma unroll
        for (int l = 0; l < LMAXC; ++l) cide[l] = (l < len) ? cid[l] : NCHAR;

        // ---- char pool: groups of 4 rows, wave-uniform skip; native vf2 adds ----
        vf2 q0 = {0.f, 0.f}, q1 = q0, q2 = q0, q3 = q0;
        #pragma unroll
        for (int g = 0; g < 3; ++g) {
            if (4 * g < len) {                        // wave-uniform branch
                #pragma unroll
                for (int l = 4 * g; l < 4 * g + 4; ++l) {
                    const uint2 rv = *(const uint2*)(smem + cide[l] * DIM + (lane << 3));
                    q0 += cvt2_fp8<false>(rv.x);
                    q1 += cvt2_fp8<true >(rv.x);
                    q2 += cvt2_fp8<false>(rv.y);
                    q3 += cvt2_fp8<true >(rv.y);
                }
            }
        }

        // ---- gate: ae = rcp(1 + exp2(we * INV_SCALE * q))  (q carries NLOG2E) ----
        const vf2 isc = {INV_SCALE, INV_SCALE};
        const vf2 weA01 = {weA.x, weA.y}, weA23 = {weA.z, weA.w};
        const vf2 weB01 = {weB.x, weB.y}, weB23 = {weB.z, weB.w};
        const vf2 x0 = (weA01 * isc) * q0;
        const vf2 x1 = (weA23 * isc) * q1;
        const vf2 x2 = (weB01 * isc) * q2;
        const vf2 x3 = (weB23 * isc) * q3;
        vf2 aeA01, aeA23, aeB01, aeB23;
        aeA01.x = rcp_fast(1.f + exp2_fast(x0.x)); aeA01.y = rcp_fast(1.f + exp2_fast(x0.y));
        aeA23.x = rcp_fast(1.f + exp2_fast(x1.x)); aeA23.y = rcp_fast(1.f + exp2_fast(x1.y));
        aeB01.x = rcp_fast(1.f + exp2_fast(x2.x)); aeB01.y = rcp_fast(1.f + exp2_fast(x2.y));
        aeB23.x = rcp_fast(1.f + exp2_fast(x3.x)); aeB23.y = rcp_fast(1.f + exp2_fast(x3.y));

        const vf4 aAv = {aeA01.x, aeA01.y, aeA23.x, aeA23.y};
        const vf4 aBv = {aeB01.x, aeB01.y, aeB23.x, aeB23.y};

        // ---- deferred store of the PREVIOUS word ----
        if (wp >= 0) {                                // wave-uniform
            float* opp = all_embed + (size_t)wp * DIM;
            *(vf4*)(opp + dA) = sAv;
            *(vf4*)(opp + dB) = sBv;
        }

        // ---- swish-weighted accumulation (native fma + DPP reduce) ----
        vf2 sd = aeA01 * pw0;
        sd += aeA23 * pw1;
        sd += aeB01 * pw2;
        sd += aeB23 * pw3;
        const float tot = wave_sum_bcast(sd.x + sd.y);
        float wa = tot + wb;
        wa = wa * rcp_fast(1.f + exp2_fast(wa * NLOG2E));   // swish
        const vf2 wa2 = {wa, wa};
        acc0 += wa2 * aeA01;
        acc1 += wa2 * aeA23;
        acc2 += wa2 * aeB01;
        acc3 += wa2 * aeB23;

        // ---- rotate: hold current output for next-iteration store ----
        wp = wu; sAv = aAv; sBv = aBv;

        w = wn; wu = wun; len = lenn;
        ci0 = m0; ci1 = m1; ci2 = m2; weA = weAn; weB = weBn;
    }

    // ---- epilogue: flush the held store ----
    if (wp >= 0) {
        float* opp = all_embed + (size_t)wp * DIM;
        *(vf4*)(opp + dA) = sAv;
        *(vf4*)(opp + dB) = sBv;
    }

    __syncthreads();
    float* red = (float*)smem;                        // 8 x 512 fp32
    *(vf2*)(red + wv * DIM + dA)     = acc0;
    *(vf2*)(red + wv * DIM + dA + 2) = acc1;
    *(vf2*)(red + wv * DIM + dB)     = acc2;
    *(vf2*)(red + wv * DIM + dB + 2) = acc3;
    __syncthreads();

    const int slice = blockIdx.x & 7;
    for (int d = threadIdx.x; d < DIM; d += 512) {
        float s = 0.f;
        #pragma unroll
        for (int k = 0; k < 8; ++k) s += red[k * DIM + d];
        atomicAdd(ww8 + slice * DIM + d, s);
    }
}

// One wave per classifier row: res[v] = dot(ww, clf_w[v]) + clf_b[v]
__global__ __launch_bounds__(256)
void clf_kernel(const float* __restrict__ ww8,    // [8, 512]
                const float* __restrict__ clf_w,  // [VOC, 512]
                const float* __restrict__ clf_b,  // [VOC]
                float*       __restrict__ res)    // [VOC]
{
    const int lane = threadIdx.x & 63;
    const int wv   = threadIdx.x >> 6;
    const int v    = (blockIdx.x << 2) + wv;
    if (v >= VOC) return;

    const int d0 = lane << 3;
    float w[8];
    #pragma unroll
    for (int j = 0; j < 8; ++j) w[j] = 0.f;
    #pragma unroll
    for (int s = 0; s < 8; ++s) {
        const float4 a = *(const float4*)(ww8 + s * DIM + d0);
        const float4 b = *(const float4*)(ww8 + s * DIM + d0 + 4);
        w[0] += a.x; w[1] += a.y; w[2] += a.z; w[3] += a.w;
        w[4] += b.x; w[5] += b.y; w[6] += b.z; w[7] += b.w;
    }

    const float* cr = clf_w + (size_t)v * DIM + d0;
    const float4 a0 = *(const float4*)(cr);
    const float4 a1 = *(const float4*)(cr + 4);
    const float p = w[0]*a0.x + w[1]*a0.y + w[2]*a0.z + w[3]*a0.w
                  + w[4]*a1.x + w[5]*a1.y + w[6]*a1.z + w[7]*a1.w;
    const float tot = wave_sum_bcast(p);
    if (lane == 0) res[v] = tot + clf_b[v];
}

extern "C" void kernel_launch(void* const* d_in, const int* in_sizes, int n_in,
                              void* d_out, int out_size, void* d_ws, size_t ws_size,
                              hipStream_t stream) {
    const int*   word_ids  = (const int*)  d_in[0];
    const int*   char_ids  = (const int*)  d_in[1];
    const int*   char_lens = (const int*)  d_in[2];
    const float* wtab      = (const float*)d_in[3];
    const float* ctab      = (const float*)d_in[4];
    const float* cpw       = (const float*)d_in[5];
    const float* cpb       = (const float*)d_in[6];
    const float* wpw       = (const float*)d_in[7];
    const float* wpb       = (const float*)d_in[8];
    const float* clf_w     = (const float*)d_in[9];
    const float* clf_b     = (const float*)d_in[10];

    const int n = in_sizes[0];                    // 50000 words
    float* out       = (float*)d_out;
    float* all_embed = out;                       // [n, 512]
    float* res       = out + (size_t)n * DIM;     // [VOC]
    float* ws        = (float*)d_ws;

    setup_kernel<<<NCHAR + 1, 256, 0, stream>>>(ctab, cpw, cpb, ws);

    fused_word_kernel<<<1024, 512, 0, stream>>>(
        word_ids, char_ids, char_lens, wtab,
        wpw, wpb, ws, all_embed, ws + WW8_OFF, n);

    clf_kernel<<<(VOC + 3) / 4, 256, 0, stream>>>(ws + WW8_OFF, clf_w, clf_b, res);
}

// Round 24
// 37.832 us; speedup vs baseline: 1.0489x; 1.0489x over previous
//
#include <hip/hip_runtime.h>
#include <math.h>

#define LMAXC 12
#define DIM   512
#define VOC   1552
#define NCHAR 80
#define SCALE     4096.0f
#define INV_SCALE (1.0f/4096.0f)
#define NLOG2E    (-1.4426950408889634f)

typedef float vf4 __attribute__((ext_vector_type(4)));
typedef float vf2 __attribute__((ext_vector_type(2)));
typedef unsigned short ushort_t;

// ws layout (float units):
//   [0, 4096)     ww8 accumulator slices (8 x 512 fp32)
//   byte 16384    u8 table: 81 rows x 512 fp8 bytes, COLUMN-PERMUTED
//   [14464, ...)  wt2 = bf16(wtab * INV_SCALE * -log2e), same permutation
#define WW8_OFF 0
#define U_BYTE_OFF 16384
#define WT_OFF  14464

__device__ __forceinline__ float rcp_fast(float x) {
#if __has_builtin(__builtin_amdgcn_rcpf)
    return __builtin_amdgcn_rcpf(x);
#else
    return 1.0f / x;
#endif
}
__device__ __forceinline__ float exp2_fast(float x) {
#if __has_builtin(__builtin_amdgcn_exp2f)
    return __builtin_amdgcn_exp2f(x);
#else
    return __expf(x * 0.69314718056f);
#endif
}

__device__ __forceinline__ ushort_t f2bf(float f) {   // round-to-nearest-even
    unsigned u = __float_as_uint(f);
    u = (u + 0x7fffu + ((u >> 16) & 1u)) >> 16;
    return (ushort_t)u;
}

// Wave-wide sum via DPP (VALU-only) -> uniform value (readlane 63).
__device__ __forceinline__ float wave_sum_bcast(float x) {
    float s = x;
    s += __int_as_float(__builtin_amdgcn_update_dpp(0, __float_as_int(s), 0x111, 0xf, 0xf, true)); // row_shr:1
    s += __int_as_float(__builtin_amdgcn_update_dpp(0, __float_as_int(s), 0x112, 0xf, 0xf, true)); // row_shr:2
    s += __int_as_float(__builtin_amdgcn_update_dpp(0, __float_as_int(s), 0x114, 0xf, 0xf, true)); // row_shr:4
    s += __int_as_float(__builtin_amdgcn_update_dpp(0, __float_as_int(s), 0x118, 0xf, 0xf, true)); // row_shr:8
    s += __int_as_float(__builtin_amdgcn_update_dpp(0, __float_as_int(s), 0x142, 0xf, 0xf, true)); // row_bcast:15
    s += __int_as_float(__builtin_amdgcn_update_dpp(0, __float_as_int(s), 0x143, 0xf, 0xf, true)); // row_bcast:31
    return __int_as_float(__builtin_amdgcn_readlane(__float_as_int(s), 63));
}

#if __has_builtin(__builtin_amdgcn_cvt_pk_fp8_f32) && __has_builtin(__builtin_amdgcn_cvt_pk_f32_fp8)
#define HW_FP8 1
#else
#define HW_FP8 0
#endif

#if !HW_FP8
__device__ __forceinline__ unsigned char f2fp8_sw(float f) {
    unsigned u = __float_as_uint(f);
    unsigned s = (u >> 24) & 0x80u;
    float a = fabsf(f);
    if (a < 0.015625f) return (unsigned char)s;
    if (a > 448.f) a = 448.f;
    u = __float_as_uint(a);
    u = u + 0x7ffffu + ((u >> 20) & 1u);
    int e8 = (int)(u >> 23) - 120;
    if (e8 <= 0) return (unsigned char)s;
    if (e8 > 15) e8 = 15;
    return (unsigned char)(s | (e8 << 3) | ((u >> 20) & 7u));
}
__device__ __forceinline__ float fp8_to_f32_sw(unsigned b) {
    unsigned e = (b >> 3) & 15u, m = b & 7u, s = (b & 0x80u) << 24;
    if (e == 0) return __uint_as_float(s);
    return __uint_as_float(s | ((e + 120u) << 23) | (m << 20));
}
#endif

// HI must be a compile-time constant for the builtin.
template<bool HI>
__device__ __forceinline__ vf2 cvt2_fp8(unsigned w32) {
#if HW_FP8
    return __builtin_amdgcn_cvt_pk_f32_fp8((int)w32, HI);
#else
    vf2 r;
    if (HI) { r.x = fp8_to_f32_sw((w32 >> 16) & 0xffu); r.y = fp8_to_f32_sw(w32 >> 24); }
    else    { r.x = fp8_to_f32_sw(w32 & 0xffu);         r.y = fp8_to_f32_sw((w32 >> 8) & 0xffu); }
    return r;
#endif
}

__device__ __forceinline__ ushort_t pack2_fp8(float f0, float f1) {
#if HW_FP8
    return (ushort_t)(__builtin_amdgcn_cvt_pk_fp8_f32(f0, f1, 0, false) & 0xffffu);
#else
    return (ushort_t)(f2fp8_sw(f0) | ((unsigned)f2fp8_sw(f1) << 8));
#endif
}

// grid = NCHAR + 1 + 388 blocks
__global__ __launch_bounds__(256)
void setup_kernel(const float* __restrict__ ctab,
                  const float* __restrict__ cpw,
                  const float* __restrict__ cpb,
                  const float* __restrict__ wtab,
                  float*       __restrict__ ws)
{
    __shared__ float red[4];
    const int b   = blockIdx.x;
    const int tid = threadIdx.x;
    unsigned char* u8 = (unsigned char*)ws + U_BYTE_OFF;

    if (b < NCHAR) {
        const float a0 = ctab[b * DIM + 2 * tid];
        const float a1 = ctab[b * DIM + 2 * tid + 1];
        float p = a0 * cpw[2 * tid] + a1 * cpw[2 * tid + 1];
        #pragma unroll
        for (int off = 32; off > 0; off >>= 1) p += __shfl_xor(p, off, 64);
        if ((tid & 63) == 0) red[tid >> 6] = p;
        __syncthreads();
        const float s = (red[0] + red[1] + red[2] + red[3] + cpb[0]) * SCALE;
        const int q   = (tid < 128) ? (tid >> 1) : ((tid - 128) >> 1);
        const int pos = 8 * q + ((tid & 1) << 1) + ((tid < 128) ? 0 : 4);
        ((ushort_t*)(u8 + b * DIM))[pos >> 1] = pack2_fp8(s * a0, s * a1);
    } else if (b == NCHAR) {
        for (int i = tid; i < 8 * DIM; i += 256) ws[WW8_OFF + i] = 0.f;
        if (tid < 128) ((unsigned int*)(u8 + NCHAR * DIM))[tid] = 0u;  // zeros row
    } else {
        const int r0 = (b - NCHAR - 1) * 4;
        ushort_t* wt16 = (ushort_t*)(ws + WT_OFF);
        for (int rr = r0; rr < r0 + 4; ++rr) {
            #pragma unroll
            for (int h = 0; h < 2; ++h) {
                const int d   = h * 256 + tid;
                const int pos = 8 * (tid >> 2) + h * 4 + (tid & 3);
                wt16[rr * DIM + pos] = f2bf(wtab[rr * DIM + d] * INV_SCALE * NLOG2E);
            }
        }
    }
}

// unpack bf16 pair (one u32) -> vf2
__device__ __forceinline__ vf2 bf2_unpack(unsigned v) {
    vf2 r;
    r.x = __uint_as_float(v << 16);
    r.y = __uint_as_float(v & 0xffff0000u);
    return r;
}

// R19 structure + native-vf2 math + group-of-4 char loop + exp2-folded gate.
__global__ __launch_bounds__(512)
void fused_word_kernel(const int*   __restrict__ word_ids,
                       const int*   __restrict__ char_ids,
                       const int*   __restrict__ char_lens,
                       const float* __restrict__ wpw,
                       const float* __restrict__ wpb,
                       const float* __restrict__ ws,
                       float*       __restrict__ all_embed, // [N, 512]
                       float*       __restrict__ ww8,       // [8, 512]
                       int n)
{
    __shared__ __align__(16) unsigned char smem[41472];   // 81 rows x 512 fp8 (permuted)

    {
        const uint4* src = (const uint4*)((const unsigned char*)ws + U_BYTE_OFF);
        uint4* dst = (uint4*)smem;
        for (int i = threadIdx.x; i < 2592; i += 512) dst[i] = src[i];
    }
    __syncthreads();

    const int lane = threadIdx.x & 63;
    const int wv   = threadIdx.x >> 6;               // 0..7
    const int dA   = lane << 2;                      // dims [4l, 4l+4)
    const int dB   = 256 + (lane << 2);
    const ushort_t* wt16 = (const ushort_t*)(ws + WT_OFF);

    // word_proj weights as pairs
    const vf2 pw0 = *(const vf2*)(wpw + dA);
    const vf2 pw1 = *(const vf2*)(wpw + dA + 2);
    const vf2 pw2 = *(const vf2*)(wpw + dB);
    const vf2 pw3 = *(const vf2*)(wpw + dB + 2);
    const float wb = wpb[0];

    vf2 acc0 = {0.f, 0.f}, acc1 = acc0, acc2 = acc0, acc3 = acc0;

    const int gw0     = (blockIdx.x << 3) + wv;
    const int gstride = gridDim.x << 3;

    int wu = 0, len = 0;
    int4 ci0 = {0,0,0,0}, ci1 = ci0, ci2 = ci0;
    uint4 wvec = {0,0,0,0};

    // deferred-store state
    int wp = -1;
    vf4 sAv = {0.f,0.f,0.f,0.f}, sBv = sAv;

    int w = gw0;
    if (w < n) {
        wu  = __builtin_amdgcn_readfirstlane(w);
        const int wid = word_ids[wu];
        len = char_lens[wu];
        const int4* cp = (const int4*)(char_ids + (size_t)wu * LMAXC);
        ci0 = cp[0]; ci1 = cp[1]; ci2 = cp[2];
        wvec = *(const uint4*)(wt16 + (size_t)wid * DIM + (lane << 3));
    }

    while (w < n) {
        const int wn   = w + gstride;
        const int wun  = __builtin_amdgcn_readfirstlane(wn < n ? wn : 0);
        const int widn = word_ids[wun];
        const int lenn = char_lens[wun];
        const int4* cpn = (const int4*)(char_ids + (size_t)wun * LMAXC);
        const int4 m0 = cpn[0], m1 = cpn[1], m2 = cpn[2];
        const uint4 wvecn = *(const uint4*)(wt16 + (size_t)widn * DIM + (lane << 3));

        const int cid[LMAXC] = {ci0.x, ci0.y, ci0.z, ci0.w,
                                ci1.x, ci1.y, ci1.z, ci1.w,
                                ci2.x, ci2.y, ci2.z, ci2.w};
        int cide[LMAXC];
        #pragma unroll
        for (int l = 0; l < LMAXC; ++l) cide[l] = (l < len) ? cid[l] : NCHAR;

        // ---- char pool: groups of 4 rows, wave-uniform skip; native vf2 adds ----
        vf2 q0 = {0.f, 0.f}, q1 = q0, q2 = q0, q3 = q0;
        #pragma unroll
        for (int g = 0; g < 3; ++g) {
            if (4 * g < len) {                        // wave-uniform branch
                #pragma unroll
                for (int l = 4 * g; l < 4 * g + 4; ++l) {
                    const uint2 rv = *(const uint2*)(smem + cide[l] * DIM + (lane << 3));
                    q0 += cvt2_fp8<false>(rv.x);
                    q1 += cvt2_fp8<true >(rv.x);
                    q2 += cvt2_fp8<false>(rv.y);
                    q3 += cvt2_fp8<true >(rv.y);
                }
            }
        }

        // ---- gate: ae = rcp(1 + exp2(we2 * p))  (we2 pre-scaled by -log2e) ----
        const vf2 x0 = bf2_unpack(wvec.x) * q0;
        const vf2 x1 = bf2_unpack(wvec.y) * q1;
        const vf2 x2 = bf2_unpack(wvec.z) * q2;
        const vf2 x3 = bf2_unpack(wvec.w) * q3;
        vf2 aeA01, aeA23, aeB01, aeB23;
        aeA01.x = rcp_fast(1.f + exp2_fast(x0.x)); aeA01.y = rcp_fast(1.f + exp2_fast(x0.y));
        aeA23.x = rcp_fast(1.f + exp2_fast(x1.x)); aeA23.y = rcp_fast(1.f + exp2_fast(x1.y));
        aeB01.x = rcp_fast(1.f + exp2_fast(x2.x)); aeB01.y = rcp_fast(1.f + exp2_fast(x2.y));
        aeB23.x = rcp_fast(1.f + exp2_fast(x3.x)); aeB23.y = rcp_fast(1.f + exp2_fast(x3.y));

        const vf4 aAv = {aeA01.x, aeA01.y, aeA23.x, aeA23.y};
        const vf4 aBv = {aeB01.x, aeB01.y, aeB23.x, aeB23.y};

        // ---- deferred store of the PREVIOUS word ----
        if (wp >= 0) {                                // wave-uniform
            float* opp = all_embed + (size_t)wp * DIM;
            *(vf4*)(opp + dA) = sAv;
            *(vf4*)(opp + dB) = sBv;
        }

        // ---- swish-weighted accumulation (native fma + DPP reduce) ----
        vf2 sd = aeA01 * pw0;
        sd += aeA23 * pw1;
        sd += aeB01 * pw2;
        sd += aeB23 * pw3;
        const float tot = wave_sum_bcast(sd.x + sd.y);
        float wa = tot + wb;
        wa = wa * rcp_fast(1.f + exp2_fast(wa * NLOG2E));   // swish
        const vf2 wa2 = {wa, wa};
        acc0 += wa2 * aeA01;
        acc1 += wa2 * aeA23;
        acc2 += wa2 * aeB01;
        acc3 += wa2 * aeB23;

        // ---- rotate: hold current output for next-iteration store ----
        wp = wu; sAv = aAv; sBv = aBv;

        w = wn; wu = wun; len = lenn;
        ci0 = m0; ci1 = m1; ci2 = m2; wvec = wvecn;
    }

    // ---- epilogue: flush the held store ----
    if (wp >= 0) {
        float* opp = all_embed + (size_t)wp * DIM;
        *(vf4*)(opp + dA) = sAv;
        *(vf4*)(opp + dB) = sBv;
    }

    __syncthreads();
    float* red = (float*)smem;                        // 8 x 512 fp32
    *(vf2*)(red + wv * DIM + dA)     = acc0;
    *(vf2*)(red + wv * DIM + dA + 2) = acc1;
    *(vf2*)(red + wv * DIM + dB)     = acc2;
    *(vf2*)(red + wv * DIM + dB + 2) = acc3;
    __syncthreads();

    const int slice = blockIdx.x & 7;
    for (int d = threadIdx.x; d < DIM; d += 512) {
        float s = 0.f;
        #pragma unroll
        for (int k = 0; k < 8; ++k) s += red[k * DIM + d];
        atomicAdd(ww8 + slice * DIM + d, s);
    }
}

// One wave per classifier row: res[v] = dot(ww, clf_w[v]) + clf_b[v]
__global__ __launch_bounds__(256)
void clf_kernel(const float* __restrict__ ww8,    // [8, 512]
                const float* __restrict__ clf_w,  // [VOC, 512]
                const float* __restrict__ clf_b,  // [VOC]
                float*       __restrict__ res)    // [VOC]
{
    const int lane = threadIdx.x & 63;
    const int wv   = threadIdx.x >> 6;
    const int v    = (blockIdx.x << 2) + wv;
    if (v >= VOC) return;

    const int d0 = lane << 3;
    float w[8];
    #pragma unroll
    for (int j = 0; j < 8; ++j) w[j] = 0.f;
    #pragma unroll
    for (int s = 0; s < 8; ++s) {
        const float4 a = *(const float4*)(ww8 + s * DIM + d0);
        const float4 b = *(const float4*)(ww8 + s * DIM + d0 + 4);
        w[0] += a.x; w[1] += a.y; w[2] += a.z; w[3] += a.w;
        w[4] += b.x; w[5] += b.y; w[6] += b.z; w[7] += b.w;
    }

    const float* cr = clf_w + (size_t)v * DIM + d0;
    const float4 a0 = *(const float4*)(cr);
    const float4 a1 = *(const float4*)(cr + 4);
    const float p = w[0]*a0.x + w[1]*a0.y + w[2]*a0.z + w[3]*a0.w
                  + w[4]*a1.x + w[5]*a1.y + w[6]*a1.z + w[7]*a1.w;
    const float tot = wave_sum_bcast(p);
    if (lane == 0) res[v] = tot + clf_b[v];
}

extern "C" void kernel_launch(void* const* d_in, const int* in_sizes, int n_in,
                              void* d_out, int out_size, void* d_ws, size_t ws_size,
                              hipStream_t stream) {
    const int*   word_ids  = (const int*)  d_in[0];
    const int*   char_ids  = (const int*)  d_in[1];
    const int*   char_lens = (const int*)  d_in[2];
    const float* wtab      = (const float*)d_in[3];
    const float* ctab      = (const float*)d_in[4];
    const float* cpw       = (const float*)d_in[5];
    const float* cpb       = (const float*)d_in[6];
    const float* wpw       = (const float*)d_in[7];
    const float* wpb       = (const float*)d_in[8];
    const float* clf_w     = (const float*)d_in[9];
    const float* clf_b     = (const float*)d_in[10];

    const int n = in_sizes[0];                    // 50000 words
    float* out       = (float*)d_out;
    float* all_embed = out;                       // [n, 512]
    float* res       = out + (size_t)n * DIM;     // [VOC]
    float* ws        = (float*)d_ws;

    setup_kernel<<<NCHAR + 1 + (VOC / 4), 256, 0, stream>>>(ctab, cpw, cpb, wtab, ws);

    fused_word_kernel<<<1024, 512, 0, stream>>>(
        word_ids, char_ids, char_lens,
        wpw, wpb, ws, all_embed, ws + WW8_OFF, n);

    clf_kernel<<<(VOC + 3) / 4, 256, 0, stream>>>(ws + WW8_OFF, clf_w, clf_b, res);
}